// Round 1
// baseline (100.391 us; speedup 1.0000x reference)
//
#include <hip/hip_runtime.h>
#include <math.h>

// FGN layer: res = (X @ W^T + bias) * g ; g = exp(-sum_i ((x-c)*min(ic,1e8))^2)
// B=1024, IN=256, OUT=1024, fp32. Compute-bound on the fp32 vector ALU
// (no fp32 MFMA on CDNA4). 64x64 output tile / block, 4x4 per thread,
// K-tile=32 staged via LDS transposed to [k][row] (stride 68 words:
// 16B-aligned float4 reads, <=2-way bank aliasing on reads = free).

constexpr int BT = 64;   // batch-rows per block
constexpr int ZT = 64;   // out-cols per block
constexpr int KT = 32;   // k-tile
constexpr int STR = 68;  // LDS row stride in words (mult of 4 for b128 align)

__global__ __launch_bounds__(256)
void fgn_kernel(const float* __restrict__ X, const float* __restrict__ W,
                const float* __restrict__ Bias, const float* __restrict__ C,
                const float* __restrict__ IC, float* __restrict__ Out,
                int B, int IN, int OUT)
{
    __shared__ float Xs[KT * STR];
    __shared__ float Ws[KT * STR];
    __shared__ float Cs[KT * STR];
    __shared__ float Is[KT * STR];

    const int ti = threadIdx.x;
    const int b0 = blockIdx.y * BT;
    const int z0 = blockIdx.x * ZT;
    const int rg = ti >> 4;          // 0..15 row group
    const int cg = ti & 15;          // 0..15 col group
    const int r0 = rg * 4;
    const int c0 = cg * 4;

    float accL[4][4] = {};
    float accG[4][4] = {};

    for (int k0 = 0; k0 < IN; k0 += KT) {
        __syncthreads();
        // ---- stage 4 tiles (each 64 rows x KT k), transposed to [k][row] ----
        #pragma unroll
        for (int it = 0; it < 2; ++it) {
            const int f   = ti + 256 * it;     // float4 index 0..511
            const int row = f >> 3;            // 0..63
            const int kq  = (f & 7) * 4;       // 0,4,...,28
            const size_t gxb = (size_t)(b0 + row) * IN + k0 + kq;
            const size_t gzb = (size_t)(z0 + row) * IN + k0 + kq;
            float4 vx = *(const float4*)&X[gxb];
            float4 vw = *(const float4*)&W[gzb];
            float4 vc = *(const float4*)&C[gzb];
            float4 vi = *(const float4*)&IC[gzb];
            // clamp per reference: min(inv_covar, 1/EPS)
            vi.x = fminf(vi.x, 1e8f); vi.y = fminf(vi.y, 1e8f);
            vi.z = fminf(vi.z, 1e8f); vi.w = fminf(vi.w, 1e8f);

            Xs[(kq+0)*STR + row] = vx.x; Xs[(kq+1)*STR + row] = vx.y;
            Xs[(kq+2)*STR + row] = vx.z; Xs[(kq+3)*STR + row] = vx.w;
            Ws[(kq+0)*STR + row] = vw.x; Ws[(kq+1)*STR + row] = vw.y;
            Ws[(kq+2)*STR + row] = vw.z; Ws[(kq+3)*STR + row] = vw.w;
            Cs[(kq+0)*STR + row] = vc.x; Cs[(kq+1)*STR + row] = vc.y;
            Cs[(kq+2)*STR + row] = vc.z; Cs[(kq+3)*STR + row] = vc.w;
            Is[(kq+0)*STR + row] = vi.x; Is[(kq+1)*STR + row] = vi.y;
            Is[(kq+2)*STR + row] = vi.z; Is[(kq+3)*STR + row] = vi.w;
        }
        __syncthreads();

        // ---- compute ----
        #pragma unroll 4
        for (int kk = 0; kk < KT; ++kk) {
            float4 x4 = *(const float4*)&Xs[kk*STR + r0];
            float4 w4 = *(const float4*)&Ws[kk*STR + c0];
            float4 c4 = *(const float4*)&Cs[kk*STR + c0];
            float4 i4 = *(const float4*)&Is[kk*STR + c0];
            const float xa[4] = {x4.x, x4.y, x4.z, x4.w};
            const float wa[4] = {w4.x, w4.y, w4.z, w4.w};
            const float ca[4] = {c4.x, c4.y, c4.z, c4.w};
            const float ia[4] = {i4.x, i4.y, i4.z, i4.w};
            #pragma unroll
            for (int i = 0; i < 4; ++i) {
                #pragma unroll
                for (int j = 0; j < 4; ++j) {
                    accL[i][j] = fmaf(xa[i], wa[j], accL[i][j]);
                    float t = (xa[i] - ca[j]) * ia[j];
                    accG[i][j] = fmaf(t, t, accG[i][j]);
                }
            }
        }
    }

    // ---- epilogue ----
    float bias4[4];
    *(float4*)bias4 = *(const float4*)&Bias[z0 + c0];
    float* OutR = Out;
    float* OutG = Out + (size_t)B * OUT;
    #pragma unroll
    for (int i = 0; i < 4; ++i) {
        float tr[4], tg[4];
        #pragma unroll
        for (int j = 0; j < 4; ++j) {
            float g = expf(-accG[i][j]);
            float l = accL[i][j] + bias4[j];
            tg[j] = g;
            tr[j] = l * g;
        }
        const size_t off = (size_t)(b0 + r0 + i) * OUT + z0 + c0;
        *(float4*)&OutR[off] = make_float4(tr[0], tr[1], tr[2], tr[3]);
        *(float4*)&OutG[off] = make_float4(tg[0], tg[1], tg[2], tg[3]);
    }
}

extern "C" void kernel_launch(void* const* d_in, const int* in_sizes, int n_in,
                              void* d_out, int out_size, void* d_ws, size_t ws_size,
                              hipStream_t stream) {
    const float* X    = (const float*)d_in[0];
    const float* W    = (const float*)d_in[1];
    const float* Bias = (const float*)d_in[2];
    const float* C    = (const float*)d_in[3];
    const float* IC   = (const float*)d_in[4];
    float* Out = (float*)d_out;

    const int OUT = in_sizes[2];
    const int IN  = in_sizes[1] / OUT;
    const int B   = in_sizes[0] / IN;

    dim3 grid(OUT / ZT, B / BT);
    fgn_kernel<<<grid, 256, 0, stream>>>(X, W, Bias, C, IC, Out, B, IN, OUT);
}

// Round 2
// 76.833 us; speedup vs baseline: 1.3066x; 1.3066x over previous
//
#include <hip/hip_runtime.h>
#include <math.h>

// FGN layer via bf16 MFMA:
//   res = (X @ W^T + bias) * g
//   g   = exp(-(A' @ Gw^T + const_z)),  A' = [X | X^2],  Gw = [-2*c*s^2 | s^2],
//   s = min(ic, 1e8),  const_z = sum_i c^2 s^2.
// B=1024, IN=256, OUT=1024 fp32 in/out; intermediates bf16 in d_ws.
// Main kernel: 32x32 tile per 64-thread block (2x2 MFMA 16x16x32), no LDS,
// fragments loaded directly from L2-resident workspace.

typedef __attribute__((ext_vector_type(8))) short short8;
typedef __attribute__((ext_vector_type(4))) float floatx4;

#define BDIM   1024
#define INDIM  256
#define OUTDIM 1024
#define AK     512   // A' row length: [x | x^2]
#define WK     256   // W row length
#define GK     512   // Gw row length: [-2cs^2 | s^2]

__device__ __forceinline__ unsigned short f2bf(float f) {
    union { float f; unsigned u; } v; v.f = f;
    unsigned r = v.u + 0x7FFFu + ((v.u >> 16) & 1u);   // RNE
    return (unsigned short)(r >> 16);
}

// Fused preprocessing.
// Blocks [0,256): convert X -> A' = [bf16(x) | bf16(x^2)]   (each thread: 4 elems)
// Blocks [256,512): per out-row z transform: Wb=bf16(W), Gw, const_z (1 wave/row)
__global__ __launch_bounds__(256)
void fgn_prep(const float* __restrict__ X, const float* __restrict__ W,
              const float* __restrict__ C, const float* __restrict__ IC,
              unsigned short* __restrict__ Ap, unsigned short* __restrict__ Wb,
              unsigned short* __restrict__ Gw, float* __restrict__ Cz)
{
    const int bid = blockIdx.x;
    if (bid < 256) {
        const int f   = bid * 256 + threadIdx.x;   // 0..65535 float4-chunks
        const int row = f >> 6;                    // 0..1023
        const int kq  = (f & 63) << 2;             // 0..252
        float4 x = *(const float4*)&X[row * INDIM + kq];
        ushort4 a, b;
        a.x = f2bf(x.x);      a.y = f2bf(x.y);      a.z = f2bf(x.z);      a.w = f2bf(x.w);
        b.x = f2bf(x.x*x.x);  b.y = f2bf(x.y*x.y);  b.z = f2bf(x.z*x.z);  b.w = f2bf(x.w*x.w);
        *(ushort4*)&Ap[row * AK + kq]         = a;
        *(ushort4*)&Ap[row * AK + INDIM + kq] = b;
    } else {
        const int z    = (bid - 256) * 4 + (threadIdx.x >> 6);  // 0..1023
        const int lane = threadIdx.x & 63;
        const int k    = lane << 2;                             // 0..252
        float4 w  = *(const float4*)&W [z * INDIM + k];
        float4 c  = *(const float4*)&C [z * INDIM + k];
        float4 ic = *(const float4*)&IC[z * INDIM + k];
        float s0 = fminf(ic.x, 1e8f), s1 = fminf(ic.y, 1e8f);
        float s2 = fminf(ic.z, 1e8f), s3 = fminf(ic.w, 1e8f);
        float q0 = s0*s0, q1 = s1*s1, q2 = s2*s2, q3 = s3*s3;
        ushort4 wv, w2v, s2v;
        wv.x  = f2bf(w.x);            wv.y  = f2bf(w.y);
        wv.z  = f2bf(w.z);            wv.w  = f2bf(w.w);
        w2v.x = f2bf(-2.f*c.x*q0);    w2v.y = f2bf(-2.f*c.y*q1);
        w2v.z = f2bf(-2.f*c.z*q2);    w2v.w = f2bf(-2.f*c.w*q3);
        s2v.x = f2bf(q0);             s2v.y = f2bf(q1);
        s2v.z = f2bf(q2);             s2v.w = f2bf(q3);
        *(ushort4*)&Wb[z * WK + k]         = wv;
        *(ushort4*)&Gw[z * GK + k]         = w2v;
        *(ushort4*)&Gw[z * GK + INDIM + k] = s2v;
        float cc = c.x*c.x*q0 + c.y*c.y*q1 + c.z*c.z*q2 + c.w*c.w*q3;
        #pragma unroll
        for (int off = 32; off; off >>= 1) cc += __shfl_xor(cc, off);
        if (lane == 0) Cz[z] = cc;
    }
}

__global__ __launch_bounds__(64)
void fgn_main(const unsigned short* __restrict__ Ap, const unsigned short* __restrict__ Wb,
              const unsigned short* __restrict__ Gw, const float* __restrict__ Bias,
              const float* __restrict__ Cz, float* __restrict__ Out)
{
    const int n0   = blockIdx.x * 32;   // out-feature tile
    const int m0   = blockIdx.y * 32;   // batch tile
    const int lane = threadIdx.x;
    const int r    = lane & 15;
    const int q    = lane >> 4;

    // fragment base pointers (short8 units; k-step 32 shorts = 4 short8)
    const short8* A0 = (const short8*)(Ap + (size_t)(m0 +      r) * AK) + q;
    const short8* A1 = (const short8*)(Ap + (size_t)(m0 + 16 + r) * AK) + q;
    const short8* G0 = (const short8*)(Gw + (size_t)(n0 +      r) * GK) + q;
    const short8* G1 = (const short8*)(Gw + (size_t)(n0 + 16 + r) * GK) + q;
    const short8* W0 = (const short8*)(Wb + (size_t)(n0 +      r) * WK) + q;
    const short8* W1 = (const short8*)(Wb + (size_t)(n0 + 16 + r) * WK) + q;

    floatx4 zero = {0.f, 0.f, 0.f, 0.f};
    floatx4 accL[2][2] = {{zero, zero}, {zero, zero}};
    floatx4 accG[2][2] = {{zero, zero}, {zero, zero}};

    // k in [0,256): both GEMMs share a-frags
    #pragma unroll
    for (int kk = 0; kk < 8; ++kk) {
        short8 a0 = A0[kk * 4];
        short8 a1 = A1[kk * 4];
        short8 g0 = G0[kk * 4];
        short8 g1 = G1[kk * 4];
        short8 w0 = W0[kk * 4];
        short8 w1 = W1[kk * 4];
        accG[0][0] = __builtin_amdgcn_mfma_f32_16x16x32_bf16(a0, g0, accG[0][0], 0, 0, 0);
        accG[0][1] = __builtin_amdgcn_mfma_f32_16x16x32_bf16(a0, g1, accG[0][1], 0, 0, 0);
        accG[1][0] = __builtin_amdgcn_mfma_f32_16x16x32_bf16(a1, g0, accG[1][0], 0, 0, 0);
        accG[1][1] = __builtin_amdgcn_mfma_f32_16x16x32_bf16(a1, g1, accG[1][1], 0, 0, 0);
        accL[0][0] = __builtin_amdgcn_mfma_f32_16x16x32_bf16(a0, w0, accL[0][0], 0, 0, 0);
        accL[0][1] = __builtin_amdgcn_mfma_f32_16x16x32_bf16(a0, w1, accL[0][1], 0, 0, 0);
        accL[1][0] = __builtin_amdgcn_mfma_f32_16x16x32_bf16(a1, w0, accL[1][0], 0, 0, 0);
        accL[1][1] = __builtin_amdgcn_mfma_f32_16x16x32_bf16(a1, w1, accL[1][1], 0, 0, 0);
    }
    // k in [256,512): Gaussian GEMM only (x^2 vs s^2 half)
    #pragma unroll
    for (int kk = 8; kk < 16; ++kk) {
        short8 a0 = A0[kk * 4];
        short8 a1 = A1[kk * 4];
        short8 g0 = G0[kk * 4];
        short8 g1 = G1[kk * 4];
        accG[0][0] = __builtin_amdgcn_mfma_f32_16x16x32_bf16(a0, g0, accG[0][0], 0, 0, 0);
        accG[0][1] = __builtin_amdgcn_mfma_f32_16x16x32_bf16(a0, g1, accG[0][1], 0, 0, 0);
        accG[1][0] = __builtin_amdgcn_mfma_f32_16x16x32_bf16(a1, g0, accG[1][0], 0, 0, 0);
        accG[1][1] = __builtin_amdgcn_mfma_f32_16x16x32_bf16(a1, g1, accG[1][1], 0, 0, 0);
    }

    // epilogue: C/D layout col = lane&15, row = q*4 + reg
    float bias[2], cz[2];
    bias[0] = Bias[n0 + r];      bias[1] = Bias[n0 + 16 + r];
    cz[0]   = Cz[n0 + r];        cz[1]   = Cz[n0 + 16 + r];
    float* OutR = Out;
    float* OutG = Out + (size_t)BDIM * OUTDIM;
    #pragma unroll
    for (int mt = 0; mt < 2; ++mt) {
        #pragma unroll
        for (int nt = 0; nt < 2; ++nt) {
            const int n = n0 + nt * 16 + r;
            #pragma unroll
            for (int reg = 0; reg < 4; ++reg) {
                const int m = m0 + mt * 16 + q * 4 + reg;
                float gexp = expf(-(accG[mt][nt][reg] + cz[nt]));
                float l    = accL[mt][nt][reg] + bias[nt];
                OutR[(size_t)m * OUTDIM + n] = l * gexp;
                OutG[(size_t)m * OUTDIM + n] = gexp;
            }
        }
    }
}

extern "C" void kernel_launch(void* const* d_in, const int* in_sizes, int n_in,
                              void* d_out, int out_size, void* d_ws, size_t ws_size,
                              hipStream_t stream) {
    const float* X    = (const float*)d_in[0];
    const float* W    = (const float*)d_in[1];
    const float* Bias = (const float*)d_in[2];
    const float* C    = (const float*)d_in[3];
    const float* IC   = (const float*)d_in[4];
    float* Out = (float*)d_out;

    unsigned short* Ap = (unsigned short*)d_ws;                  // 1024*512 = 1 MB
    unsigned short* Wb = Ap + (size_t)BDIM * AK;                 // 1024*256 = 0.5 MB
    unsigned short* Gw = Wb + (size_t)OUTDIM * WK;               // 1024*512 = 1 MB
    float*          Cz = (float*)(Gw + (size_t)OUTDIM * GK);     // 4 KB

    fgn_prep<<<512, 256, 0, stream>>>(X, W, C, IC, Ap, Wb, Gw, Cz);
    dim3 grid(OUTDIM / 32, BDIM / 32);
    fgn_main<<<grid, 64, 0, stream>>>(Ap, Wb, Gw, Bias, Cz, Out);
}